// Round 14
// baseline (97.275 us; speedup 1.0000x reference)
//
#include <hip/hip_runtime.h>
#include <hip/hip_fp16.h>
#include <math.h>
#include <stdint.h>

#define IN_DIM  256
#define OUT_DIM 256
#define NROWS   68     // G + K
#define NT      71     // knot count
#define BATCH   512
#define KPAD    96     // per-channel k, padded to 3 x K32
#define NCG     32     // 32 cgroups x 8 channels
#define PITCH   776    // Y row pitch in f16 (768 + 8; stride = 4 banks -> 2-way, free)
#define PART_FLOATS (NCG * BATCH * OUT_DIM)       // 16 MB of partials
#define WB_SHORTS   (IN_DIM * OUT_DIM * KPAD)     // 12.6 MB f16

typedef _Float16 f16x8 __attribute__((ext_vector_type(8)));
typedef float    f32x4 __attribute__((ext_vector_type(4)));

// ---- Kernel A (unchanged from R13, PASSED): w[k][c][o] fp32 ->
//      wb[c][kb][o][32k] f16, zero-padded k>=68. ----
__global__ __launch_bounds__(256) void cvt_kernel(const float* __restrict__ w,
                                                  unsigned short* __restrict__ wb) {
  __shared__ unsigned short l16[NROWS][264];
  const int c = blockIdx.x;
  const int t = threadIdx.x;
  const int o4 = (t & 63) * 4;
  for (int k = (t >> 6); k < NROWS; k += 4) {
    const float4 v = *(const float4*)(w + ((size_t)k * IN_DIM + c) * OUT_DIM + o4);
    l16[k][o4 + 0] = __half_as_ushort(__float2half_rn(v.x));
    l16[k][o4 + 1] = __half_as_ushort(__float2half_rn(v.y));
    l16[k][o4 + 2] = __half_as_ushort(__float2half_rn(v.z));
    l16[k][o4 + 3] = __half_as_ushort(__float2half_rn(v.w));
  }
  __syncthreads();
  #pragma unroll
  for (int i = 0; i < 12; ++i) {
    const int idx = t + 256 * i;        // 3072 uint4 total
    const int kb  = idx >> 10;
    const int o   = (idx >> 2) & 255;
    const int g   = idx & 3;
    const int k8  = kb * 32 + g * 8;
    uint32_t hl[4];
    #pragma unroll
    for (int j = 0; j < 4; ++j) {
      const int ka = k8 + 2 * j, k2 = ka + 1;
      const uint32_t lo = (ka < NROWS) ? (uint32_t)l16[ka][o] : 0u;
      const uint32_t hi = (k2 < NROWS) ? (uint32_t)l16[k2][o] : 0u;
      hl[j] = lo | (hi << 16);
    }
    *(uint4*)(wb + (((size_t)(c * 3 + kb) * 256 + o) * 32 + g * 8)) =
        make_uint4(hl[0], hl[1], hl[2], hl[3]);
  }
}

// ---- Kernel B: MFMA gather v3 — ONE Y for all 8 channels (K=768), ZERO
//      inner barriers. Grid 256 = 8 btile x 32 cg, 512 threads.
//      Build Y[64][768] once (basis threads scatter 5 f16 directly), then
//      stream 24 k-blocks: 2 contiguous-1KB A-frag global loads + 4
//      ds_read_b128 + 8 MFMA each, compiler-pipelined, no sync. Operand
//      roles / C-D map byte-identical to R12/R13 (both PASSED). ----
__global__ __launch_bounds__(512) void kan_gather_kernel(
    const float* __restrict__ x, const unsigned short* __restrict__ wbu,
    const float* __restrict__ t, float* __restrict__ part) {
  __shared__ float lt[NT];
  __shared__ char  smem[64 * PITCH * 2];        // Y_full (99.3 KB); bounce aliases

  unsigned short* Y = (unsigned short*)smem;
  float* bounce = (float*)smem;                  // 64 x 260 f32 = 66.6 KB < 99.3
  const int tid   = threadIdx.x;
  const int cg    = blockIdx.x & 31;
  const int btile = blockIdx.x >> 5;
  const int wv    = tid >> 6;
  const int lane  = tid & 63;
  const int m16   = lane & 15;
  const int g     = lane >> 4;
  const int ob    = wv * 32;                    // wave's o-base

  if (tid < NT) lt[tid] = t[tid];
  {  // zero Y: 6208 uint4
    uint4* y4 = (uint4*)smem;
    for (int i = tid; i < 64 * PITCH / 8; i += 512)
      y4[i] = make_uint4(0u, 0u, 0u, 0u);
  }
  __syncthreads();

  // ---- basis for (c = tid>>6, b = tid&63), scattered STRAIGHT into Y ----
  {
    const int c = tid >> 6, bb = tid & 63;
    const float xv = x[(size_t)(btile * 64 + bb) * IN_DIM + cg * 8 + c];
    int i = 3 + (int)floorf((xv + 1.0f) * 32.0f);
    i = i < 3 ? 3 : (i > 66 ? 66 : i);
    while (i > 3 && xv < lt[i]) --i;
    while (i < 66 && xv >= lt[i + 1]) ++i;
    float N0 = 1.f, N1 = 0.f, N2 = 0.f, N3 = 0.f;
    { const float l1 = xv - lt[i], r1 = lt[i + 1] - xv;
      const float tp = N0 / (r1 + l1); N1 = l1 * tp; N0 = r1 * tp; }
    { const float l1 = xv - lt[i], l2 = xv - lt[i - 1];
      const float r1 = lt[i + 1] - xv, r2 = lt[i + 2] - xv;
      float saved = 0.f;
      const float tp0 = N0 / (r1 + l2); const float n0 = saved + r1 * tp0; saved = l2 * tp0;
      const float tp1 = N1 / (r2 + l1); const float n1 = saved + r2 * tp1; saved = l1 * tp1;
      N0 = n0; N1 = n1; N2 = saved; }
    { const float l1 = xv - lt[i], l2 = xv - lt[i - 1], l3 = xv - lt[i - 2];
      const float r1 = lt[i + 1] - xv, r2 = lt[i + 2] - xv, r3 = lt[i + 3] - xv;
      float saved = 0.f;
      const float tp0 = N0 / (r1 + l3); const float n0 = saved + r1 * tp0; saved = l3 * tp0;
      const float tp1 = N1 / (r2 + l2); const float n1 = saved + r2 * tp1; saved = l2 * tp1;
      const float tp2 = N2 / (r3 + l1); const float n2 = saved + r3 * tp2; saved = l1 * tp2;
      N0 = n0; N1 = n1; N2 = n2; N3 = saved; }
    unsigned short* yr = Y + (size_t)bb * PITCH + c * KPAD;
    const int base = i - 3;
    yr[base + 0] = __half_as_ushort(__float2half_rn(N0));
    yr[base + 1] = __half_as_ushort(__float2half_rn(N1));
    yr[base + 2] = __half_as_ushort(__float2half_rn(N2));
    yr[base + 3] = __half_as_ushort(__float2half_rn(N3));
    yr[67]       = __half_as_ushort(__float2half_rn(xv / (1.0f + expf(-xv))));
  }
  __syncthreads();   // Y complete; no further sync until epilogue

  // ---- barrier-free K=768 stream: 24 k-blocks ----
  const uint4* wbu4 = (const uint4*)wbu;
  f32x4 acc[2][4];
  #pragma unroll
  for (int ot = 0; ot < 2; ++ot)
    #pragma unroll
    for (int bt = 0; bt < 4; ++bt) acc[ot][bt] = f32x4{0.f, 0.f, 0.f, 0.f};

  #pragma unroll 8
  for (int j = 0; j < 24; ++j) {
    const size_t rowb = ((size_t)(cg * 24 + j)) * 256;
    const uint4 af0 = wbu4[(rowb + ob + m16) * 4 + g];
    const uint4 af1 = wbu4[(rowb + ob + 16 + m16) * 4 + g];
    #pragma unroll
    for (int bt = 0; bt < 4; ++bt) {
      const f16x8 bf = *(const f16x8*)(Y + (size_t)(bt * 16 + m16) * PITCH + j * 32 + g * 8);
      acc[0][bt] = __builtin_amdgcn_mfma_f32_16x16x32_f16(
          __builtin_bit_cast(f16x8, af0), bf, acc[0][bt], 0, 0, 0);
      acc[1][bt] = __builtin_amdgcn_mfma_f32_16x16x32_f16(
          __builtin_bit_cast(f16x8, af1), bf, acc[1][bt], 0, 0, 0);
    }
  }
  __syncthreads();   // all Y reads done before bounce overwrites smem

  // ---- epilogue (R13's, PASSED): acc -> bounce transpose -> coalesced ----
  #pragma unroll
  for (int ot = 0; ot < 2; ++ot)
    #pragma unroll
    for (int bt = 0; bt < 4; ++bt)
      #pragma unroll
      for (int r = 0; r < 4; ++r)
        bounce[(bt * 16 + m16) * 260 + ob + ot * 16 + g * 4 + r] = acc[ot][bt][r];
  __syncthreads();
  #pragma unroll
  for (int i = 0; i < 8; ++i) {
    const int idx = tid + 512 * i;   // 4096 float4
    const int b = idx >> 6, o4 = (idx & 63) * 4;
    *(float4*)(part + ((size_t)cg * BATCH + btile * 64 + b) * OUT_DIM + o4) =
        *(const float4*)(bounce + b * 260 + o4);
  }
}

// ---- Kernel C: reduce the 32 c-group partials into out ----
__global__ __launch_bounds__(256) void reduce_kernel(const float* __restrict__ part,
                                                     float* __restrict__ out) {
  const int q = blockIdx.x * 256 + threadIdx.x;   // float4 index, 32768 total
  const int S = BATCH * OUT_DIM / 4;
  const float4* p = (const float4*)part;
  float4 s = p[q];
  #pragma unroll
  for (int k = 1; k < NCG; ++k) {
    const float4 a = p[q + k * S];
    s.x += a.x; s.y += a.y; s.z += a.z; s.w += a.w;
  }
  ((float4*)out)[q] = s;
}

extern "C" void kernel_launch(void* const* d_in, const int* in_sizes, int n_in,
                              void* d_out, int out_size, void* d_ws, size_t ws_size,
                              hipStream_t stream) {
  const float* x = (const float*)d_in[0];
  const float* w = (const float*)d_in[1];
  const float* t = (const float*)d_in[2];
  float* out  = (float*)d_out;
  float* part = (float*)d_ws;                                         // 16 MB
  unsigned short* wb = (unsigned short*)((float*)d_ws + PART_FLOATS);  // f16 W
  cvt_kernel<<<IN_DIM, 256, 0, stream>>>(w, wb);
  kan_gather_kernel<<<256, 512, 0, stream>>>(x, wb, t, part);
  reduce_kernel<<<BATCH * OUT_DIM / 4 / 256, 256, 0, stream>>>(part, out);
}

// Round 15
// 90.375 us; speedup vs baseline: 1.0764x; 1.0764x over previous
//
#include <hip/hip_runtime.h>
#include <math.h>
#include <stdint.h>

#define IN_DIM  256
#define OUT_DIM 256
#define NROWS   68     // G + K
#define NT      71     // knot count
#define BATCH   512
#define W_ELEMS (NROWS * IN_DIM * OUT_DIM)   // 4,456,448
#define PART_FLOATS (8 * BATCH * OUT_DIM)    // 1,048,576 floats = 4 MB

// ---- Kernel A: convert w fp32 -> packed bf16 pairs ----
__device__ __forceinline__ uint32_t bf16_rne(float f) {
  uint32_t u = __builtin_bit_cast(uint32_t, f);
  return (u + 0x7fffu + ((u >> 16) & 1u)) >> 16;   // finite inputs only
}

__global__ __launch_bounds__(256) void cvt_kernel(const float* __restrict__ w,
                                                  uint32_t* __restrict__ wb) {
  const int base = (blockIdx.x * 256 + threadIdx.x) * 8;   // 8 floats / thread
  const float4 a = *(const float4*)(w + base);
  const float4 b = *(const float4*)(w + base + 4);
  uint4 o;
  o.x = bf16_rne(a.x) | (bf16_rne(a.y) << 16);
  o.y = bf16_rne(a.z) | (bf16_rne(a.w) << 16);
  o.z = bf16_rne(b.x) | (bf16_rne(b.y) << 16);
  o.w = bf16_rne(b.z) | (bf16_rne(b.w) << 16);
  *(uint4*)(wb + base / 2) = o;
}

// ---- Kernel B: bf16 gather-accumulate. 8 b x 32 c, grid 512, ~2 waves/SIMD,
//      batch-issue of all 33 row loads per pass. Best-measured configuration
//      (89.39 us); every structural variant tested R2-R14 measured worse. ----
__device__ __forceinline__ void fma8(const uint4 q, const float y, float* acc) {
  acc[0] += y * __builtin_bit_cast(float, q.x << 16);
  acc[1] += y * __builtin_bit_cast(float, q.x & 0xffff0000u);
  acc[2] += y * __builtin_bit_cast(float, q.y << 16);
  acc[3] += y * __builtin_bit_cast(float, q.y & 0xffff0000u);
  acc[4] += y * __builtin_bit_cast(float, q.z << 16);
  acc[5] += y * __builtin_bit_cast(float, q.z & 0xffff0000u);
  acc[6] += y * __builtin_bit_cast(float, q.w << 16);
  acc[7] += y * __builtin_bit_cast(float, q.w & 0xffff0000u);
}

__global__ __launch_bounds__(256) void kan_gather_kernel(
    const float* __restrict__ x, const uint4* __restrict__ wp,
    const float* __restrict__ t, float* __restrict__ part) {
  __shared__ float  lt[NT];
  __shared__ float4 nA[32][8];   // N0..N3 per (local c, local b)
  __shared__ float  sA[32][8];   // silu(x) per local c
  __shared__ int    bA[32][8];   // i-3 per local c
  __shared__ float  red[4][2048]; // per-wave partials: [wave][b*256 + o]

  const int tid = threadIdx.x;
  const unsigned bid = blockIdx.x;
  // cchunk = bid&7 -> XCD affinity (dispatch round-robins bid%8): each XCD's
  // L2 holds only its 32-channel bf16 slice (68*32*512B = 1.1 MB).
  const int cchunk = bid & 7;
  const int bgroup = bid >> 3;   // 64 groups of 8 batch rows

  if (tid < NT) lt[tid] = t[tid];
  __syncthreads();

  // ---- Phase 1: basis for 8 b x 32 c; exactly one (b,c) pair per thread ----
  {
    const int bb = tid >> 5;
    const int cl = tid & 31;
    const float xv = x[(size_t)(bgroup * 8 + bb) * IN_DIM + cchunk * 32 + cl];
    int i = 3 + (int)floorf((xv + 1.0f) * 32.0f);
    i = i < 3 ? 3 : (i > 66 ? 66 : i);
    while (i > 3 && xv < lt[i]) --i;
    while (i < 66 && xv >= lt[i + 1]) ++i;

    float N0 = 1.f, N1 = 0.f, N2 = 0.f, N3 = 0.f;
    { // p = 1
      const float l1 = xv - lt[i];
      const float r1 = lt[i + 1] - xv;
      const float tp = N0 / (r1 + l1);
      N1 = l1 * tp; N0 = r1 * tp;
    }
    { // p = 2
      const float l1 = xv - lt[i];
      const float l2 = xv - lt[i - 1];
      const float r1 = lt[i + 1] - xv;
      const float r2 = lt[i + 2] - xv;
      float saved = 0.f;
      const float tp0 = N0 / (r1 + l2);
      const float n0 = saved + r1 * tp0; saved = l2 * tp0;
      const float tp1 = N1 / (r2 + l1);
      const float n1 = saved + r2 * tp1; saved = l1 * tp1;
      N0 = n0; N1 = n1; N2 = saved;
    }
    { // p = 3
      const float l1 = xv - lt[i];
      const float l2 = xv - lt[i - 1];
      const float l3 = xv - lt[i - 2];
      const float r1 = lt[i + 1] - xv;
      const float r2 = lt[i + 2] - xv;
      const float r3 = lt[i + 3] - xv;
      float saved = 0.f;
      const float tp0 = N0 / (r1 + l3);
      const float n0 = saved + r1 * tp0; saved = l3 * tp0;
      const float tp1 = N1 / (r2 + l2);
      const float n1 = saved + r2 * tp1; saved = l2 * tp1;
      const float tp2 = N2 / (r3 + l1);
      const float n2 = saved + r3 * tp2; saved = l1 * tp2;
      N0 = n0; N1 = n1; N2 = n2; N3 = saved;
    }
    nA[cl][bb] = make_float4(N0, N1, N2, N3);
    sA[cl][bb] = xv / (1.0f + expf(-xv));
    bA[cl][bb] = i - 3;
  }
  __syncthreads();

  // ---- Phase 2: wave = 2 channels/pass (half-wave each, 32 lanes x uint4 =
  //      full 256-o bf16 row), 4 passes. Per pass: batch-issue 33 loads,
  //      then all FMAs. ----
  const int wv   = tid >> 6;
  const int lane = tid & 63;
  const int half = lane >> 5;
  const int ol   = lane & 31;     // uint4 (8-o) slot: o = ol*8 + j

  float acc[8][8];
  #pragma unroll
  for (int b = 0; b < 8; ++b) {
    #pragma unroll
    for (int j = 0; j < 8; ++j) acc[b][j] = 0.f;
  }

  for (int pp = 0; pp < 4; ++pp) {
    const int cl = wv * 8 + pp * 2 + half;            // local c, 0..31
    const uint32_t cbase = (uint32_t)((cchunk * 32 + cl) * 32 + ol);
    const uint4 q4 = wp[cbase + 67u * 8192u];         // silu row

    // batch-issue: all 32 spline-row loads, no intervening VALU use
    uint4 q[8][4];
    #pragma unroll
    for (int b = 0; b < 8; ++b) {
      const uint32_t rb = cbase + ((uint32_t)bA[cl][b] << 13);
      q[b][0] = wp[rb];
      q[b][1] = wp[rb +  8192u];
      q[b][2] = wp[rb + 16384u];
      q[b][3] = wp[rb + 24576u];
    }
    // consume: loads long since landed
    #pragma unroll
    for (int b = 0; b < 8; ++b) {
      const float4 yv = nA[cl][b];
      const float  ys = sA[cl][b];
      fma8(q[b][0], yv.x, acc[b]);
      fma8(q[b][1], yv.y, acc[b]);
      fma8(q[b][2], yv.z, acc[b]);
      fma8(q[b][3], yv.w, acc[b]);
      fma8(q4,      ys,   acc[b]);
    }
  }

  // fold the two half-waves (partner lane holds the pass's other channel)
  #pragma unroll
  for (int b = 0; b < 8; ++b) {
    #pragma unroll
    for (int j = 0; j < 8; ++j)
      acc[b][j] += __shfl_xor(acc[b][j], 32, 64);
  }

  if (half == 0) {
    #pragma unroll
    for (int b = 0; b < 8; ++b) {
      #pragma unroll
      for (int j = 0; j < 8; ++j)
        red[wv][b * 256 + ol * 8 + j] = acc[b][j];
    }
  }
  __syncthreads();

  // ---- Phase 3: sum the 4 waves, store c-chunk partial (streaming) ----
  {
    const int b  = tid >> 5;         // local batch row
    const int oo = tid & 31;         // 8-float slot
    float s[8] = {0.f, 0.f, 0.f, 0.f, 0.f, 0.f, 0.f, 0.f};
    #pragma unroll
    for (int w2 = 0; w2 < 4; ++w2) {
      const float* rr = &red[w2][b * 256 + oo * 8];
      #pragma unroll
      for (int j = 0; j < 8; ++j) s[j] += rr[j];
    }
    float* dst = part + ((size_t)cchunk * BATCH + bgroup * 8 + b) * OUT_DIM + oo * 8;
    *(float4*)dst       = make_float4(s[0], s[1], s[2], s[3]);
    *(float4*)(dst + 4) = make_float4(s[4], s[5], s[6], s[7]);
  }
}

// ---- Kernel C: reduce the 8 c-chunk partials into out ----
__global__ __launch_bounds__(256) void reduce_kernel(const float* __restrict__ part,
                                                     float* __restrict__ out) {
  const int q = blockIdx.x * 256 + threadIdx.x;   // float4 index, 32768 total
  const int S = BATCH * OUT_DIM / 4;              // float4 stride per slice
  const float4* p = (const float4*)part;
  float4 s = p[q];
  #pragma unroll
  for (int k = 1; k < 8; ++k) {
    const float4 a = p[q + k * S];
    s.x += a.x; s.y += a.y; s.z += a.z; s.w += a.w;
  }
  ((float4*)out)[q] = s;
}

extern "C" void kernel_launch(void* const* d_in, const int* in_sizes, int n_in,
                              void* d_out, int out_size, void* d_ws, size_t ws_size,
                              hipStream_t stream) {
  const float* x = (const float*)d_in[0];
  const float* w = (const float*)d_in[1];
  const float* t = (const float*)d_in[2];
  float* out  = (float*)d_out;
  float* part = (float*)d_ws;                       // 4 MB of partials
  uint32_t* wb = (uint32_t*)d_ws + PART_FLOATS;     // bf16 weights after
  cvt_kernel<<<W_ELEMS / (256 * 8), 256, 0, stream>>>(w, wb);
  kan_gather_kernel<<<BATCH / 8 * 8, 256, 0, stream>>>(x, (const uint4*)wb, t, part);
  reduce_kernel<<<BATCH * OUT_DIM / 4 / 256, 256, 0, stream>>>(part, out);
}